// Round 12
// baseline (72.470 us; speedup 1.0000x reference)
//
#include <hip/hip_runtime.h>
#include <hip/hip_bf16.h>

#define B_    4
#define T_    4096
#define D_    2048
#define NTOK  (B_ * T_)
#define NREC  3
#define BAL_W 0.01f
#define Z_W   0.001f
#define TPB   16              // tokens per block
#define SLC   16              // D-slices per token (128 floats each)
#define ABLK  (NTOK / TPB)    // 1024 blocks
#define ATHR  (TPB * SLC)     // 256 threads

typedef __attribute__((ext_vector_type(4))) float float4v;

// Phase A (GEMV layout): thread (ti, s) owns token t = bid*16+ti, slice s
// (128 contiguous floats). Dot accumulates IN-LANE (no cross-lane reduce in
// the stream loop). 2-deep chunk pipeline with named A/B register buffers.
// W staged in LDS once per block; W reads are 4-way-broadcast ds_read_b128.
// Per-block LDS fold + epilogue; one float4 loss partial per block.
__global__ __launch_bounds__(ATHR) void tcr12_phaseA(
    const float* __restrict__ x,              // [NTOK, D_] f32
    const float* __restrict__ w,              // [NREC, D_] f32
    const int* __restrict__ ridx_p,
    float* __restrict__ out_f,                // d_out as f32
    float4v* __restrict__ partials)           // [ABLK] in d_ws
{
    __shared__ float s_w[NREC * D_];          // 24 KB
    {
        const float4v* src = reinterpret_cast<const float4v*>(w);
        float4v*       dst = reinterpret_cast<float4v*>(s_w);
#pragma unroll
        for (int i = 0; i < (NREC * D_ / 4) / ATHR; ++i)   // 6
            dst[i * ATHR + threadIdx.x] =
                __builtin_nontemporal_load(src + i * ATHR + threadIdx.x);
    }
    __syncthreads();

    const int tid = threadIdx.x;
    const int ti  = tid & (TPB - 1);          // token within block
    const int s   = tid >> 4;                 // slice 0..15
    const int t   = blockIdx.x * TPB + ti;

    const float4v* xv =
        reinterpret_cast<const float4v*>(x + (size_t)t * D_ + s * (D_ / SLC));
    const float* wbase = s_w + s * (D_ / SLC);

    float a0 = 0.f, a1 = 0.f, a2 = 0.f;

    float4v A[8], Bv[8];                      // named buffers: static indexing
#pragma unroll
    for (int u = 0; u < 8; ++u) A[u]  = __builtin_nontemporal_load(xv + u);
#pragma unroll
    for (int u = 0; u < 8; ++u) Bv[u] = __builtin_nontemporal_load(xv + 8 + u);

    auto proc = [&](const float4v (&buf)[8], int jb) {
#pragma unroll
        for (int u = 0; u < 8; ++u) {
            const int off = (jb + u) * 4;
            const float4v w0 = *reinterpret_cast<const float4v*>(wbase + off);
            const float4v w1 = *reinterpret_cast<const float4v*>(wbase + D_ + off);
            const float4v w2 = *reinterpret_cast<const float4v*>(wbase + 2 * D_ + off);
#pragma unroll
            for (int e = 0; e < 4; ++e) {
                a0 = fmaf(buf[u][e], w0[e], a0);
                a1 = fmaf(buf[u][e], w1[e], a1);
                a2 = fmaf(buf[u][e], w2[e], a2);
            }
        }
    };

    proc(A, 0);                               // consume chunk 0
#pragma unroll
    for (int u = 0; u < 8; ++u) A[u] = __builtin_nontemporal_load(xv + 16 + u);
    proc(Bv, 8);                              // consume chunk 1
#pragma unroll
    for (int u = 0; u < 8; ++u) Bv[u] = __builtin_nontemporal_load(xv + 24 + u);
    proc(A, 16);                              // consume chunk 2
    proc(Bv, 24);                             // consume chunk 3

    // Fold 16 slices per token in LDS, then per-token epilogue.
    __shared__ float   s_dots[TPB][SLC + 1][3];   // +1 pad: spread banks
    __shared__ float4v s_p[TPB];
    s_dots[ti][s][0] = a0;
    s_dots[ti][s][1] = a1;
    s_dots[ti][s][2] = a2;
    __syncthreads();

    if (tid < TPB) {
        float d0 = 0.f, d1 = 0.f, d2 = 0.f;
#pragma unroll
        for (int q = 0; q < SLC; ++q) {
            d0 += s_dots[tid][q][0];
            d1 += s_dots[tid][q][1];
            d2 += s_dots[tid][q][2];
        }
        const int ridx = ridx_p[0];
        const int jc   = ridx < (NREC - 1) ? (ridx < 0 ? 0 : ridx) : (NREC - 1);
        const int t2   = blockIdx.x * TPB + tid;

        const float m  = fmaxf(d0, fmaxf(d1, d2));
        const float e0 = expf(d0 - m), e1 = expf(d1 - m), e2 = expf(d2 - m);
        const float sm = e0 + e1 + e2;
        const float z  = m + logf(sm);
        int   assign = 0; float best = d0;
        if (d1 > best) { best = d1; assign = 1; }
        if (d2 > best) { best = d2; assign = 2; }
        const float g = (jc == 0 ? e0 : (jc == 1 ? e1 : e2)) / sm;   // > 0

        out_f[NTOK + t2]     = (assign >= ridx) ? g : -g;  // sign = inactive
        out_f[2 * NTOK + t2] = d0;

        float4v p;
        p[0] = z * z;
        p[1] = (assign == 0) ? 1.f : 0.f;
        p[2] = (assign == 1) ? 1.f : 0.f;
        p[3] = (assign == 2) ? 1.f : 0.f;
        s_p[tid] = p;
    }
    __syncthreads();
    if (tid == 0) {
        float4v q = s_p[0];
#pragma unroll
        for (int i = 1; i < TPB; ++i) {
            const float4v r2 = s_p[i];
#pragma unroll
            for (int e = 0; e < 4; ++e) q[e] += r2[e];
        }
        partials[blockIdx.x] = q;
    }
}

// Phase B: per-batch stable compaction via shuffle-based scan (2 barriers),
// plus loss reduction (block 0 folds ABLK==1024 partials).
__global__ __launch_bounds__(1024) void tcr12_phaseB(
    const float4v* __restrict__ partials,     // [ABLK]
    float* __restrict__ out_f)
{
    __shared__ int      s_ws[16];
    __shared__ unsigned s_sel[T_];
    __shared__ float    s_g[T_];
    __shared__ float4v  s_red[16];
    const int b    = blockIdx.x;
    const int tid  = threadIdx.x;
    const int lane = tid & 63;
    const int wv   = tid >> 6;                // 16 waves
    const int base = b * T_;

    float g[4]; int f[4]; int loc = 0;
#pragma unroll
    for (int r = 0; r < 4; ++r) {
        g[r] = out_f[NTOK + base + tid * 4 + r];
        f[r] = (g[r] > 0.f) ? 1 : 0;          // sign set => inactive
        loc += f[r];
    }
    int isc = loc;
#pragma unroll
    for (int off = 1; off < 64; off <<= 1) {
        const int u = __shfl_up(isc, off);
        if (lane >= off) isc += u;
    }
    if (lane == 63) s_ws[wv] = isc;
    __syncthreads();
    int wbase = 0, cnt = 0;
#pragma unroll
    for (int i = 0; i < 16; ++i) {
        const int v = s_ws[i];
        cnt += v;
        if (i < wv) wbase += v;
    }
    int pos = wbase + isc - loc;              // exclusive prefix
#pragma unroll
    for (int r = 0; r < 4; ++r) {
        if (f[r] && (unsigned)pos < (unsigned)T_) {
            s_sel[pos] = (unsigned)(tid * 4 + r);
            s_g[pos]   = g[r];
            ++pos;
        }
    }
    __syncthreads();

#pragma unroll
    for (int r = 0; r < 4; ++r) {
        const int k = tid + r * 1024;         // coalesced
        float selv, gv;
        if (cnt == 0) { selv = 0.f; gv = 0.f; }
        else {
            const int kk = (k < cnt) ? k : (cnt - 1);
            selv = (float)s_sel[kk];
            gv   = s_g[kk];
        }
        out_f[base + k]        = selv;        // selected
        out_f[NTOK + base + k] = gv;          // gate_weights (compacted)
    }

    // Loss reduction: block 0 folds ABLK==1024 partials (one per thread).
    float4v p;
    if (b == 0) p = partials[tid];
    else { p[0] = 0.f; p[1] = 0.f; p[2] = 0.f; p[3] = 0.f; }
#pragma unroll
    for (int off = 32; off > 0; off >>= 1) {
#pragma unroll
        for (int e = 0; e < 4; ++e) p[e] += __shfl_xor(p[e], off);
    }
    if (lane == 0) s_red[wv] = p;
    __syncthreads();
    if (b == 0 && tid == 0) {
        float4v q = s_red[0];
#pragma unroll
        for (int i = 1; i < 16; ++i) {
            const float4v r2 = s_red[i];
#pragma unroll
            for (int e = 0; e < 4; ++e) q[e] += r2[e];
        }
        const float inv = 1.0f / (float)NTOK;
        float aux = 0.f;
#pragma unroll
        for (int n = 0; n < NREC; ++n) {
            const float d = q[1 + n] * inv - (1.0f / 3.0f);
            aux = fmaf(d, d, aux);
        }
        out_f[3 * NTOK + 0] = BAL_W * aux;
        out_f[3 * NTOK + 1] = Z_W * q[0] * inv;
    }
}

extern "C" void kernel_launch(void* const* d_in, const int* in_sizes, int n_in,
                              void* d_out, int out_size, void* d_ws, size_t ws_size,
                              hipStream_t stream) {
    const float* x  = (const float*)d_in[0];
    const float* w  = (const float*)d_in[1];
    const int* ridx = (const int*)d_in[2];
    float* out_f = (float*)d_out;
    float4v* partials = (float4v*)d_ws;   // 16 KB of ws

    tcr12_phaseA<<<dim3(ABLK), dim3(ATHR), 0, stream>>>(x, w, ridx, out_f, partials);
    tcr12_phaseB<<<dim3(B_),   dim3(1024), 0, stream>>>(partials, out_f);
}

// Round 13
// 40.814 us; speedup vs baseline: 1.7756x; 1.7756x over previous
//
#include <hip/hip_runtime.h>
#include <hip/hip_bf16.h>

#define B_    4
#define T_    4096
#define D_    2048
#define NTOK  (B_ * T_)
#define NREC  3
#define BAL_W 0.01f
#define Z_W   0.001f
#define PBLK  512             // phaseA blocks (2 resident/CU, persistent)
#define PTHR  512             // 8 waves/block; 4096 waves total, 4 tokens/wave

typedef __attribute__((ext_vector_type(4))) float float4v;

// Phase A: persistent grid (one launch generation, zero block churn).
// W staged in LDS ONCE per block. Each wave owns 4 consecutive tokens and
// runs 2 generations of the r9 pattern: 16 contiguous nt dwordx4 loads up
// front (8 KB/token x2), FMA vs LDS-broadcast W, 6-sum butterfly, epilogue
// on lanes 0+32 in parallel. No barriers / re-staging between generations.
// d_out FLOAT32 (49154 elems):
//   [0, NTOK)        : selected (phase B)
//   [NTOK, 2*NTOK)   : gate, sign = inactive tag (uncompacted; fixed by B)
//   [2*NTOK, 3*NTOK) : logit0
//   [3*NTOK] aux, [3*NTOK+1] z
__global__ __launch_bounds__(PTHR) void tcr13_phaseA(
    const float* __restrict__ x,              // [NTOK, D_] f32
    const float* __restrict__ w,              // [NREC, D_] f32
    const int* __restrict__ ridx_p,
    float* __restrict__ out_f,                // d_out as f32
    float4v* __restrict__ partials)           // [PBLK] in d_ws
{
    __shared__ float s_w[NREC * D_];          // 24 KB, staged once
    {
        const float4v* src = reinterpret_cast<const float4v*>(w);
        float4v*       dst = reinterpret_cast<float4v*>(s_w);
#pragma unroll
        for (int i = 0; i < (NREC * D_ / 4) / PTHR; ++i)   // 1536/512 = 3
            dst[i * PTHR + threadIdx.x] =
                __builtin_nontemporal_load(src + i * PTHR + threadIdx.x);
    }
    __syncthreads();

    const int ridx = ridx_p[0];
    const int jc   = ridx < (NREC - 1) ? (ridx < 0 ? 0 : ridx) : (NREC - 1);
    const int lane = threadIdx.x & 63;
    const int wv   = threadIdx.x >> 6;                     // wave in block (0..7)
    const int wid  = (blockIdx.x * PTHR + threadIdx.x) >> 6;
    const int tw   = wid * 4;                              // 4 consecutive tokens

    float z2 = 0.f, c0 = 0.f, c1 = 0.f, c2 = 0.f;

#pragma unroll
    for (int gen = 0; gen < 2; ++gen) {
        const int t0 = tw + gen * 2;
        const float* xp0 = x + (size_t)t0 * D_;
        float4v xv0[8], xv1[8];
#pragma unroll
        for (int j = 0; j < 8; ++j) {
            xv0[j] = __builtin_nontemporal_load(
                reinterpret_cast<const float4v*>(xp0 + (j * 64 + lane) * 4));
            xv1[j] = __builtin_nontemporal_load(
                reinterpret_cast<const float4v*>(xp0 + D_ + (j * 64 + lane) * 4));
        }

        float a0 = 0.f, a1 = 0.f, a2 = 0.f;   // token t0
        float b0 = 0.f, b1 = 0.f, b2 = 0.f;   // token t0+1
#pragma unroll
        for (int j = 0; j < 8; ++j) {
            const int kb = (j * 64 + lane) * 4;
            const float4v w0 = *reinterpret_cast<const float4v*>(&s_w[kb]);
            const float4v w1 = *reinterpret_cast<const float4v*>(&s_w[D_ + kb]);
            const float4v w2 = *reinterpret_cast<const float4v*>(&s_w[2 * D_ + kb]);
#pragma unroll
            for (int e = 0; e < 4; ++e) {
                a0 = fmaf(xv0[j][e], w0[e], a0);
                a1 = fmaf(xv0[j][e], w1[e], a1);
                a2 = fmaf(xv0[j][e], w2[e], a2);
                b0 = fmaf(xv1[j][e], w0[e], b0);
                b1 = fmaf(xv1[j][e], w1[e], b1);
                b2 = fmaf(xv1[j][e], w2[e], b2);
            }
        }
#pragma unroll
        for (int off = 32; off > 0; off >>= 1) {
            a0 += __shfl_xor(a0, off);
            a1 += __shfl_xor(a1, off);
            a2 += __shfl_xor(a2, off);
            b0 += __shfl_xor(b0, off);
            b1 += __shfl_xor(b1, off);
            b2 += __shfl_xor(b2, off);
        }
        // Lanes 0 and 32 run the epilogue in parallel (one per token).
        if ((lane & 31) == 0) {
            const int hi = lane >> 5;          // 0 -> t0, 1 -> t0+1
            const int t  = t0 + hi;
            const float l0 = hi ? b0 : a0;
            const float l1 = hi ? b1 : a1;
            const float l2 = hi ? b2 : a2;

            const float m  = fmaxf(l0, fmaxf(l1, l2));
            const float e0 = expf(l0 - m), e1 = expf(l1 - m), e2 = expf(l2 - m);
            const float s  = e0 + e1 + e2;
            const float z  = m + logf(s);
            int   assign = 0; float best = l0;
            if (l1 > best) { best = l1; assign = 1; }
            if (l2 > best) { best = l2; assign = 2; }
            const float g = (jc == 0 ? e0 : (jc == 1 ? e1 : e2)) / s;   // > 0

            out_f[NTOK + t]     = (assign >= ridx) ? g : -g;  // sign = inactive
            out_f[2 * NTOK + t] = l0;

            z2 += z * z;
            if (assign == 0) c0 += 1.f; else if (assign == 1) c1 += 1.f; else c2 += 1.f;
        }
    }

    // combine lane0+lane32 partials, then block reduce (8 waves) -> 1 float4
    z2 += __shfl_xor(z2, 32);
    c0 += __shfl_xor(c0, 32);
    c1 += __shfl_xor(c1, 32);
    c2 += __shfl_xor(c2, 32);
    __shared__ float4v s_part[PTHR / 64];
    if (lane == 0) {
        float4v p; p[0] = z2; p[1] = c0; p[2] = c1; p[3] = c2;
        s_part[wv] = p;
    }
    __syncthreads();
    if (threadIdx.x == 0) {
        float4v p = s_part[0];
#pragma unroll
        for (int i = 1; i < PTHR / 64; ++i) {
            const float4v q = s_part[i];
#pragma unroll
            for (int e = 0; e < 4; ++e) p[e] += q[e];
        }
        partials[blockIdx.x] = p;
    }
}

// Phase B: per-batch stable compaction via shuffle-based scan (2 barriers),
// plus loss reduction (block 0 folds PBLK==512 partials).
__global__ __launch_bounds__(1024) void tcr13_phaseB(
    const float4v* __restrict__ partials,     // [PBLK]
    float* __restrict__ out_f)
{
    __shared__ int      s_ws[16];
    __shared__ unsigned s_sel[T_];
    __shared__ float    s_g[T_];
    __shared__ float4v  s_red[16];
    const int b    = blockIdx.x;
    const int tid  = threadIdx.x;
    const int lane = tid & 63;
    const int wv   = tid >> 6;                // 16 waves
    const int base = b * T_;

    float g[4]; int f[4]; int loc = 0;
#pragma unroll
    for (int r = 0; r < 4; ++r) {
        g[r] = out_f[NTOK + base + tid * 4 + r];
        f[r] = (g[r] > 0.f) ? 1 : 0;          // sign set => inactive
        loc += f[r];
    }
    int isc = loc;
#pragma unroll
    for (int off = 1; off < 64; off <<= 1) {
        const int u = __shfl_up(isc, off);
        if (lane >= off) isc += u;
    }
    if (lane == 63) s_ws[wv] = isc;
    __syncthreads();
    int wbase = 0, cnt = 0;
#pragma unroll
    for (int i = 0; i < 16; ++i) {
        const int v = s_ws[i];
        cnt += v;
        if (i < wv) wbase += v;
    }
    int pos = wbase + isc - loc;              // exclusive prefix
#pragma unroll
    for (int r = 0; r < 4; ++r) {
        if (f[r] && (unsigned)pos < (unsigned)T_) {
            s_sel[pos] = (unsigned)(tid * 4 + r);
            s_g[pos]   = g[r];
            ++pos;
        }
    }
    __syncthreads();

#pragma unroll
    for (int r = 0; r < 4; ++r) {
        const int k = tid + r * 1024;         // coalesced
        float selv, gv;
        if (cnt == 0) { selv = 0.f; gv = 0.f; }
        else {
            const int kk = (k < cnt) ? k : (cnt - 1);
            selv = (float)s_sel[kk];
            gv   = s_g[kk];
        }
        out_f[base + k]        = selv;        // selected
        out_f[NTOK + base + k] = gv;          // gate_weights (compacted)
    }

    // Loss reduction: block 0 folds PBLK==512 partials.
    float4v p;
    if (b == 0 && tid < PBLK) p = partials[tid];
    else { p[0] = 0.f; p[1] = 0.f; p[2] = 0.f; p[3] = 0.f; }
#pragma unroll
    for (int off = 32; off > 0; off >>= 1) {
#pragma unroll
        for (int e = 0; e < 4; ++e) p[e] += __shfl_xor(p[e], off);
    }
    if (lane == 0) s_red[wv] = p;
    __syncthreads();
    if (b == 0 && tid == 0) {
        float4v q = s_red[0];
#pragma unroll
        for (int i = 1; i < 16; ++i) {
            const float4v r2 = s_red[i];
#pragma unroll
            for (int e = 0; e < 4; ++e) q[e] += r2[e];
        }
        const float inv = 1.0f / (float)NTOK;
        float aux = 0.f;
#pragma unroll
        for (int n = 0; n < NREC; ++n) {
            const float d = q[1 + n] * inv - (1.0f / 3.0f);
            aux = fmaf(d, d, aux);
        }
        out_f[3 * NTOK + 0] = BAL_W * aux;
        out_f[3 * NTOK + 1] = Z_W * q[0] * inv;
    }
}

extern "C" void kernel_launch(void* const* d_in, const int* in_sizes, int n_in,
                              void* d_out, int out_size, void* d_ws, size_t ws_size,
                              hipStream_t stream) {
    const float* x  = (const float*)d_in[0];
    const float* w  = (const float*)d_in[1];
    const int* ridx = (const int*)d_in[2];
    float* out_f = (float*)d_out;
    float4v* partials = (float4v*)d_ws;   // 8 KB of ws

    tcr13_phaseA<<<dim3(PBLK), dim3(PTHR), 0, stream>>>(x, w, ridx, out_f, partials);
    tcr13_phaseB<<<dim3(B_),   dim3(1024), 0, stream>>>(partials, out_f);
}